// Round 11
// baseline (103.548 us; speedup 1.0000x reference)
//
#include <hip/hip_runtime.h>
#include <cstdint>

typedef unsigned int u32;
typedef float vf4 __attribute__((ext_vector_type(4)));

// ---------------------------------------------------------------------------
// Threefry-2x32 (20 rounds) — validated bit-exact vs JAX in round 1
// (jax_threefry_partitionable=True semantics).
//   split(key, n)[i]           = threefry2x32(key, (0, i))
//   random_bits(key,32,shape)e = r0 ^ r1 of threefry2x32(key, (0, e))
// ---------------------------------------------------------------------------
#define TF_R4(a,b,r1,r2,r3,r4) \
  a += b; b = (b<<r1)|(b>>(32-r1)); b ^= a; \
  a += b; b = (b<<r2)|(b>>(32-r2)); b ^= a; \
  a += b; b = (b<<r3)|(b>>(32-r3)); b ^= a; \
  a += b; b = (b<<r4)|(b>>(32-r4)); b ^= a;

__host__ __device__ inline void tf2x32(u32 k0, u32 k1, u32& x0, u32& x1) {
  const u32 k2 = k0 ^ k1 ^ 0x1BD11BDAu;
  u32 a = x0 + k0, b = x1 + k1;
  TF_R4(a,b,13,15,26,6)   a += k1; b += k2 + 1u;
  TF_R4(a,b,17,29,16,24)  a += k2; b += k0 + 2u;
  TF_R4(a,b,13,15,26,6)   a += k0; b += k1 + 3u;
  TF_R4(a,b,17,29,16,24)  a += k1; b += k2 + 4u;
  TF_R4(a,b,13,15,26,6)   a += k2; b += k0 + 5u;
  x0 = a; x1 = b;
}

__host__ __device__ inline float u01(u32 bits) {
  union { u32 u; float f; } c; c.u = (bits >> 9) | 0x3f800000u;
  return c.f - 1.0f;
}
__host__ __device__ inline u32 rbits_scalar(u32 k0, u32 k1) {
  u32 a = 0, b = 0; tf2x32(k0, k1, a, b); return a ^ b;
}

// problem constants
#define BATCH   512
#define HW      224
#define S       50176     /* 224*224 */
#define S4      12544     /* float4 per sample */
#define NTOT    25690112
#define N4      6422528   /* float4 total */
#define Q4      3136      /* float4 per quarter-sample */
#define FSTR    1152      /* ws floats per sample */
#define FIXPB   8         /* k_fix blocks per sample */

// ws layout: fdata[512][FSTR] floats.
//   [0,224)      rowmax[r]
//   [224,1120)   colmax quarter partials cm[q][224]
//   [1120,1132)  per-quarter {max, argmax-bits, min} x 4

struct AMask { unsigned long long m[8]; };   // host-computed apply flags

// ---------------------------------------------------------------------------
// Kernel 1: stats pass — round-6 proven shape (read-only streams at 6.4 TB/s).
// Block = one quarter (56 rows) of one sample; wave wv owns 14 rows; lane<56
// owns float4-column lane. Early-exit for non-apply samples (host bitmask):
// only ~half the samples are read. Writes rowmax/colmax/stats partials to ws.
// ---------------------------------------------------------------------------
__global__ __launch_bounds__(256) void k_stats(const float* __restrict__ x,
                                               float* __restrict__ fdata,
                                               AMask am) {
  const int bid = blockIdx.x;
  const int b = bid >> 2, q = bid & 3;
  if (!((am.m[b >> 6] >> (b & 63)) & 1ull)) return;   // non-apply: no stats needed

  const int t = threadIdx.x;
  const int lane = t & 63, wv = t >> 6;
  const float* __restrict__ xs = x + (size_t)b * S;
  float* __restrict__ base = fdata + (size_t)b * FSTR;
  const bool act = lane < 56;

  vf4 cmax = (vf4){0.f, 0.f, 0.f, 0.f};       // x in [0,1) -> 0 neutral
  float amax = -1.f; int aidx = 0x7fffffff; float amin = 2.f;

#pragma unroll
  for (int k = 0; k < 14; ++k) {
    const int r = q * 56 + wv * 14 + k;
    vf4 v = (vf4){-1.f, -1.f, -1.f, -1.f};
    if (act) v = ((const vf4*)(xs + (size_t)r * HW))[lane];
    float rv = fmaxf(fmaxf(v[0], v[1]), fmaxf(v[2], v[3]));
    if (act) {
      cmax[0] = fmaxf(cmax[0], v[0]); cmax[1] = fmaxf(cmax[1], v[1]);
      cmax[2] = fmaxf(cmax[2], v[2]); cmax[3] = fmaxf(cmax[3], v[3]);
      const int fb = r * HW + lane * 4;
      if (v[0] > amax) { amax = v[0]; aidx = fb; }
      if (v[1] > amax) { amax = v[1]; aidx = fb + 1; }
      if (v[2] > amax) { amax = v[2]; aidx = fb + 2; }
      if (v[3] > amax) { amax = v[3]; aidx = fb + 3; }
      amin = fminf(amin, fminf(fminf(v[0], v[1]), fminf(v[2], v[3])));
    }
    for (int off = 32; off; off >>= 1) rv = fmaxf(rv, __shfl_xor(rv, off));
    if (lane == 0) base[r] = rv;              // rowmax
  }
  for (int off = 32; off; off >>= 1) {
    float v2 = __shfl_xor(amax, off);
    int   i2 = __shfl_xor(aidx, off);
    float n2 = __shfl_xor(amin, off);
    if (v2 > amax || (v2 == amax && i2 < aidx)) { amax = v2; aidx = i2; }
    amin = fminf(amin, n2);
  }
  __shared__ vf4 cmw[4][56];
  __shared__ float wmx[4]; __shared__ int wix[4]; __shared__ float wmn[4];
  if (act) cmw[wv][lane] = cmax;
  if (lane == 0) { wmx[wv] = amax; wix[wv] = aidx; wmn[wv] = amin; }
  __syncthreads();
  if (t < 56) {
    vf4 a = cmw[0][t], c1 = cmw[1][t], c2 = cmw[2][t], c3 = cmw[3][t];
    vf4 m;
    m[0] = fmaxf(fmaxf(a[0], c1[0]), fmaxf(c2[0], c3[0]));
    m[1] = fmaxf(fmaxf(a[1], c1[1]), fmaxf(c2[1], c3[1]));
    m[2] = fmaxf(fmaxf(a[2], c1[2]), fmaxf(c2[2], c3[2]));
    m[3] = fmaxf(fmaxf(a[3], c1[3]), fmaxf(c2[3], c3[3]));
    ((vf4*)(base + 224 + q * 224))[t] = m;    // colmax quarter partial
  }
  if (t == 0) {
    float mx = wmx[0]; int ix = wix[0]; float mn = wmn[0];
    for (int wI = 1; wI < 4; ++wI) {
      if (wmx[wI] > mx || (wmx[wI] == mx && wix[wI] < ix)) { mx = wmx[wI]; ix = wix[wI]; }
      mn = fminf(mn, wmn[wI]);
    }
    base[1120 + q * 3 + 0] = mx;
    base[1120 + q * 3 + 1] = __int_as_float(ix);
    base[1120 + q * 3 + 2] = mn;
  }
}

// ---------------------------------------------------------------------------
// Kernel 2: pure flat streaming provisional writer — the dominant 309 MB.
// out = 0.6x+0.2, mask = 1 (correct everywhere outside erase boxes).
// Zero branches, zero per-sample logic, many tiny blocks (round-6 fast shape).
// ---------------------------------------------------------------------------
__global__ __launch_bounds__(256) void k_out(const float* __restrict__ x,
                                             float* __restrict__ out) {
  const int i = blockIdx.x * 256 + threadIdx.x;   // global float4 index
  const vf4 v = ((const vf4*)x)[i];
  vf4 o;
  // inp = 0.6*x + 0.2 -- no fma contraction (match XLA)
  o[0] = __fadd_rn(__fmul_rn(0.6f, v[0]), 0.2f);
  o[1] = __fadd_rn(__fmul_rn(0.6f, v[1]), 0.2f);
  o[2] = __fadd_rn(__fmul_rn(0.6f, v[2]), 0.2f);
  o[3] = __fadd_rn(__fmul_rn(0.6f, v[3]), 0.2f);
  const vf4 ones = (vf4){1.f, 1.f, 1.f, 1.f};
  __builtin_nontemporal_store(o,    &((vf4*)out)[i]);
  __builtin_nontemporal_store(ones, &((vf4*)(out + (size_t)NTOT))[i]);
}

// ---------------------------------------------------------------------------
// Kernel 3: fix the erase box only (round-9/10 verbatim — passed twice).
// FIXPB blocks per sample; derives thr/box from ws partials; rewrites box
// pixels with val > thr (bernoulli threefry inline).
// ---------------------------------------------------------------------------
__global__ __launch_bounds__(256) void k_fix(const float* __restrict__ x,
                                             float* __restrict__ out,
                                             const float* __restrict__ fdata,
                                             float factor,
                                             u32 ks0, u32 ks1,
                                             u32 kn0, u32 kn1) {
  const int bid = blockIdx.x;
  const int b = bid >> 3, qq = bid & 7;
  const int t = threadIdx.x;
  const int lane = t & 63, wv = t >> 6;

  // apply flag: pure RNG, uniform across block — cheap early out
  u32 kb0 = 0, kb1 = (u32)b; tf2x32(ks0, ks1, kb0, kb1);     // keys[b]
  u32 ka0 = 0, ka1 = 0; tf2x32(kb0, kb1, ka0, ka1);          // k_apply
  if (!(u01(rbits_scalar(ka0, ka1)) < 0.5f)) return;

  const float* __restrict__ base = fdata + (size_t)b * FSTR;
  __shared__ float rm[224], cmx[224];
  __shared__ float sc_thr; __shared__ int sc_ix;
  __shared__ int r0[4], r1[4], r2[4], r3[4];
  __shared__ int sbox[5];   // hs, he, ws, we, doit

  if (t < 224) {
    rm[t] = base[t];
    float c = base[224 + t];
    c = fmaxf(c, base[224 + 224 + t]);
    c = fmaxf(c, base[224 + 448 + t]);
    c = fmaxf(c, base[224 + 672 + t]);
    cmx[t] = c;
  }
  if (t == 0) {
    float mx = -1.f; int ix = 0x7fffffff; float mn = 2.f;
#pragma unroll
    for (int q2 = 0; q2 < 4; ++q2) {
      const float v = base[1120 + q2 * 3 + 0];
      const int   i = __float_as_int(base[1120 + q2 * 3 + 1]);
      const float n = base[1120 + q2 * 3 + 2];
      if (v > mx || (v == mx && i < ix)) { mx = v; ix = i; }
      mn = fminf(mn, n);
    }
    // thr = mx - (mx - mn) * factor -- no fma contraction (match XLA)
    sc_thr = __fsub_rn(mx, __fmul_rn(__fsub_rn(mx, mn), factor));
    sc_ix = ix;
  }
  __syncthreads();
  const float thr = sc_thr;

  // bbox of prop from rowmax/colmax
  {
    int miny = HW, maxy = -1, minx = HW, maxx = -1;
    if (t < HW) {
      if (rm[t] > thr)  { miny = t; maxy = t; }
      if (cmx[t] > thr) { minx = t; maxx = t; }
    }
    for (int off = 32; off; off >>= 1) {
      miny = min(miny, __shfl_xor(miny, off));
      maxy = max(maxy, __shfl_xor(maxy, off));
      minx = min(minx, __shfl_xor(minx, off));
      maxx = max(maxx, __shfl_xor(maxx, off));
    }
    if (lane == 0) { r0[wv] = miny; r1[wv] = maxy; r2[wv] = minx; r3[wv] = maxx; }
  }
  __syncthreads();
  if (t == 0) {
    int mny = r0[0], mxy = r1[0], mnx = r2[0], mxx = r3[0];
    for (int wI = 1; wI < 4; ++wI) {
      mny = min(mny, r0[wI]); mxy = max(mxy, r1[wI]);
      mnx = min(mnx, r2[wI]); mxx = max(mxx, r3[wI]);
    }
    const bool any = (mxy >= 0);
    const int mh2 = (mxy - mny) / 2;
    const int mw2 = (mxx - mnx) / 2;
    const bool valid = any && (mh2 > 4) && (mw2 > 4);

    u32 kh0 = 0, kh1 = 1; tf2x32(kb0, kb1, kh0, kh1);        // k_h
    u32 kw0 = 0, kw1 = 2; tf2x32(kb0, kb1, kw0, kw1);        // k_w
    const float uh = u01(rbits_scalar(kh0, kh1));
    const float uw = u01(rbits_scalar(kw0, kw1));
    const int cy = sc_ix / HW, cx = sc_ix % HW;
    const int h = 4 + (int)(uh * (float)max(mh2 - 4, 1));
    const int w = 4 + (int)(uw * (float)max(mw2 - 4, 1));
    sbox[0] = max(cy - h, 0); sbox[1] = min(cy + h, HW);
    sbox[2] = max(cx - w, 0); sbox[3] = min(cx + w, HW);
    sbox[4] = valid ? 1 : 0;
  }
  __syncthreads();
  if (!sbox[4]) return;
  const int hs = sbox[0], he = sbox[1], wss = sbox[2], wee = sbox[3];

  // rewrite erase pixels: rows hs+1..he-1 (interleaved by qq), cols wss+1..wee-1
  const int xx = wss + 1 + t;                 // wee - wss - 1 <= 223 < 256
  const bool cin = (xx < wee);
  const float* __restrict__ xs = x + (size_t)b * S;
  float* __restrict__ os = out + (size_t)b * S;
  float* __restrict__ ms = out + (size_t)NTOT + (size_t)b * S;

  for (int y = hs + 1 + qq; y < he; y += FIXPB) {
    if (cin) {
      const int pix = y * HW + xx;
      const float val = xs[pix];
      if (val > thr) {                        // erase pixel
        const float inp = __fadd_rn(__fmul_rn(0.6f, val), 0.2f);
        const float kp  = fminf(fmaxf(__fsub_rn(1.0f, inp), 0.0f), 1.0f);
        u32 c0 = 0u, c1 = (u32)b * (u32)S + (u32)pix;
        tf2x32(kn0, kn1, c0, c1);
        os[pix] = (u01(c0 ^ c1) < kp) ? inp : 0.0f;   // inp * bernoulli
        ms[pix] = 0.0f;
      }
    }
  }
}

// ---------------------------------------------------------------------------
extern "C" void kernel_launch(void* const* d_in, const int* in_sizes, int n_in,
                              void* d_out, int out_size, void* d_ws, size_t ws_size,
                              hipStream_t stream) {
  const float* x = (const float*)d_in[0];
  float* out = (float*)d_out;
  float* fdata = (float*)d_ws;

  // host-side key derivation: root = key(42) = (0,42)
  u32 kf0 = 0, kf1 = 0; tf2x32(0u, 42u, kf0, kf1);   // k_factor = split[0]
  u32 ks0 = 0, ks1 = 1; tf2x32(0u, 42u, ks0, ks1);   // k_samples = split[1]
  u32 kn0 = 0, kn1 = 2; tf2x32(0u, 42u, kn0, kn1);   // k_noise  = split[2]
  float factor = fmaxf(0.0f, u01(rbits_scalar(kf0, kf1)) * 0.5f);

  // host-side per-sample apply flags (pure RNG, deterministic)
  AMask am;
  for (int i = 0; i < 8; ++i) am.m[i] = 0ull;
  for (int b = 0; b < BATCH; ++b) {
    u32 kb0 = 0, kb1 = (u32)b; tf2x32(ks0, ks1, kb0, kb1);
    u32 ka0 = 0, ka1 = 0; tf2x32(kb0, kb1, ka0, ka1);
    if (u01(rbits_scalar(ka0, ka1)) < 0.5f) am.m[b >> 6] |= 1ull << (b & 63);
  }

  hipLaunchKernelGGL(k_stats, dim3(BATCH * 4), dim3(256), 0, stream,
                     x, fdata, am);
  hipLaunchKernelGGL(k_out, dim3(N4 / 256), dim3(256), 0, stream, x, out);
  hipLaunchKernelGGL(k_fix, dim3(BATCH * FIXPB), dim3(256), 0, stream,
                     x, out, fdata, factor, ks0, ks1, kn0, kn1);
}

// Round 12
// 69.783 us; speedup vs baseline: 1.4839x; 1.4839x over previous
//
#include <hip/hip_runtime.h>
#include <cstdint>

typedef unsigned int u32;
typedef float vf4 __attribute__((ext_vector_type(4)));

// ---------------------------------------------------------------------------
// Threefry-2x32 (20 rounds) — validated bit-exact vs JAX in round 1
// (jax_threefry_partitionable=True semantics).
//   split(key, n)[i]           = threefry2x32(key, (0, i))
//   random_bits(key,32,shape)e = r0 ^ r1 of threefry2x32(key, (0, e))
// ---------------------------------------------------------------------------
#define TF_R4(a,b,r1,r2,r3,r4) \
  a += b; b = (b<<r1)|(b>>(32-r1)); b ^= a; \
  a += b; b = (b<<r2)|(b>>(32-r2)); b ^= a; \
  a += b; b = (b<<r3)|(b>>(32-r3)); b ^= a; \
  a += b; b = (b<<r4)|(b>>(32-r4)); b ^= a;

__host__ __device__ inline void tf2x32(u32 k0, u32 k1, u32& x0, u32& x1) {
  const u32 k2 = k0 ^ k1 ^ 0x1BD11BDAu;
  u32 a = x0 + k0, b = x1 + k1;
  TF_R4(a,b,13,15,26,6)   a += k1; b += k2 + 1u;
  TF_R4(a,b,17,29,16,24)  a += k2; b += k0 + 2u;
  TF_R4(a,b,13,15,26,6)   a += k0; b += k1 + 3u;
  TF_R4(a,b,17,29,16,24)  a += k1; b += k2 + 4u;
  TF_R4(a,b,13,15,26,6)   a += k2; b += k0 + 5u;
  x0 = a; x1 = b;
}

__host__ __device__ inline float u01(u32 bits) {
  union { u32 u; float f; } c; c.u = (bits >> 9) | 0x3f800000u;
  return c.f - 1.0f;
}
__host__ __device__ inline u32 rbits_scalar(u32 k0, u32 k1) {
  u32 a = 0, b = 0; tf2x32(k0, k1, a, b); return a ^ b;
}

// problem constants
#define BATCH   512
#define HW      224
#define S       50176     /* 224*224 */
#define NTOT    25690112
#define APB     49        /* k_apply blocks per sample: S4/256 */
#define FSTR    1152      /* ws floats per sample */

struct SP { float thr; int hs, he, wss, wee, doit; int pad0, pad1; };
struct AMask { unsigned long long m[8]; };   // host-computed apply flags
// ws layout: [0, 16384) SP[512]; [16384, ...) fdata[512][FSTR] floats
//   fdata per sample: [0,224) rowmax; [224,1120) colmax quarter partials;
//                     [1120,1132) per-quarter {max, argmax-bits, min} x 4

// ---------------------------------------------------------------------------
// Kernel 1 (round-6 proven + AMask early-exit): single pass over apply
// samples only. Block = one quarter (56 rows); wave wv owns 14 rows; lane<56
// owns float4-column lane. Writes rowmax / colmax partials / quarter stats.
// ---------------------------------------------------------------------------
__global__ __launch_bounds__(256) void k_stats(const float* __restrict__ x,
                                               float* __restrict__ fdata,
                                               AMask am) {
  const int bid = blockIdx.x;
  const int b = bid >> 2, q = bid & 3;
  if (!((am.m[b >> 6] >> (b & 63)) & 1ull)) return;  // non-apply: stats unused

  const int t = threadIdx.x;
  const int lane = t & 63, wv = t >> 6;
  const float* __restrict__ xs = x + (size_t)b * S;
  float* __restrict__ base = fdata + (size_t)b * FSTR;
  const bool act = lane < 56;

  vf4 cmax = (vf4){0.f, 0.f, 0.f, 0.f};       // x in [0,1) -> 0 neutral
  float amax = -1.f; int aidx = 0x7fffffff; float amin = 2.f;

#pragma unroll
  for (int k = 0; k < 14; ++k) {
    const int r = q * 56 + wv * 14 + k;
    vf4 v = (vf4){-1.f, -1.f, -1.f, -1.f};
    if (act) v = ((const vf4*)(xs + (size_t)r * HW))[lane];
    float rv = fmaxf(fmaxf(v[0], v[1]), fmaxf(v[2], v[3]));
    if (act) {
      cmax[0] = fmaxf(cmax[0], v[0]); cmax[1] = fmaxf(cmax[1], v[1]);
      cmax[2] = fmaxf(cmax[2], v[2]); cmax[3] = fmaxf(cmax[3], v[3]);
      const int fb = r * HW + lane * 4;
      if (v[0] > amax) { amax = v[0]; aidx = fb; }
      if (v[1] > amax) { amax = v[1]; aidx = fb + 1; }
      if (v[2] > amax) { amax = v[2]; aidx = fb + 2; }
      if (v[3] > amax) { amax = v[3]; aidx = fb + 3; }
      amin = fminf(amin, fminf(fminf(v[0], v[1]), fminf(v[2], v[3])));
    }
    for (int off = 32; off; off >>= 1) rv = fmaxf(rv, __shfl_xor(rv, off));
    if (lane == 0) base[r] = rv;              // rowmax
  }
  for (int off = 32; off; off >>= 1) {
    float v2 = __shfl_xor(amax, off);
    int   i2 = __shfl_xor(aidx, off);
    float n2 = __shfl_xor(amin, off);
    if (v2 > amax || (v2 == amax && i2 < aidx)) { amax = v2; aidx = i2; }
    amin = fminf(amin, n2);
  }
  __shared__ vf4 cmw[4][56];
  __shared__ float wmx[4]; __shared__ int wix[4]; __shared__ float wmn[4];
  if (act) cmw[wv][lane] = cmax;
  if (lane == 0) { wmx[wv] = amax; wix[wv] = aidx; wmn[wv] = amin; }
  __syncthreads();
  if (t < 56) {
    vf4 a = cmw[0][t], c1 = cmw[1][t], c2 = cmw[2][t], c3 = cmw[3][t];
    vf4 m;
    m[0] = fmaxf(fmaxf(a[0], c1[0]), fmaxf(c2[0], c3[0]));
    m[1] = fmaxf(fmaxf(a[1], c1[1]), fmaxf(c2[1], c3[1]));
    m[2] = fmaxf(fmaxf(a[2], c1[2]), fmaxf(c2[2], c3[2]));
    m[3] = fmaxf(fmaxf(a[3], c1[3]), fmaxf(c2[3], c3[3]));
    ((vf4*)(base + 224 + q * 224))[t] = m;    // colmax quarter partial
  }
  if (t == 0) {
    float mx = wmx[0]; int ix = wix[0]; float mn = wmn[0];
    for (int wI = 1; wI < 4; ++wI) {
      if (wmx[wI] > mx || (wmx[wI] == mx && wix[wI] < ix)) { mx = wmx[wI]; ix = wix[wI]; }
      mn = fminf(mn, wmn[wI]);
    }
    base[1120 + q * 3 + 0] = mx;
    base[1120 + q * 3 + 1] = __int_as_float(ix);
    base[1120 + q * 3 + 2] = mn;
  }
}

// ---------------------------------------------------------------------------
// Kernel 2 (round-6 logic from ws partials + AMask fast path): one block per
// sample; derives thr / erase box; writes SP. Non-apply: doit=0 immediately
// (thr dead downstream — k_apply short-circuits on doit before reading thr).
// ---------------------------------------------------------------------------
__global__ __launch_bounds__(256) void k_box(const float* __restrict__ fdata,
                                             SP* __restrict__ sp,
                                             float factor, u32 ks0, u32 ks1,
                                             AMask am) {
  const int b = blockIdx.x;
  const int t = threadIdx.x;
  const int lane = t & 63, wv = t >> 6;

  if (!((am.m[b >> 6] >> (b & 63)) & 1ull)) {
    if (t == 0) {
      SP p; p.thr = 0.f; p.hs = 0; p.he = 0; p.wss = 0; p.wee = 0;
      p.doit = 0; p.pad0 = 0; p.pad1 = 0;
      sp[b] = p;
    }
    return;
  }

  const float* __restrict__ base = fdata + (size_t)b * FSTR;
  __shared__ float sc_thr; __shared__ int sc_ix;
  __shared__ int r0[4], r1[4], r2[4], r3[4];

  if (t == 0) {
    float mx = -1.f; int ix = 0x7fffffff; float mn = 2.f;
#pragma unroll
    for (int q2 = 0; q2 < 4; ++q2) {
      const float v = base[1120 + q2 * 3 + 0];
      const int   i = __float_as_int(base[1120 + q2 * 3 + 1]);
      const float n = base[1120 + q2 * 3 + 2];
      if (v > mx || (v == mx && i < ix)) { mx = v; ix = i; }
      mn = fminf(mn, n);
    }
    // thr = mx - (mx - mn) * factor -- no fma contraction (match XLA)
    sc_thr = __fsub_rn(mx, __fmul_rn(__fsub_rn(mx, mn), factor));
    sc_ix = ix;
  }
  __syncthreads();
  const float thr = sc_thr;

  // bbox of prop from rowmax/colmax
  int miny = HW, maxy = -1, minx = HW, maxx = -1;
  if (t < HW) {
    if (base[t] > thr) { miny = t; maxy = t; }            // row flag
    const float c0 = base[224 + t],       c1 = base[224 + 224 + t];
    const float c2 = base[224 + 448 + t], c3 = base[224 + 672 + t];
    if (fmaxf(fmaxf(c0, c1), fmaxf(c2, c3)) > thr) { minx = t; maxx = t; }
  }
  for (int off = 32; off; off >>= 1) {
    miny = min(miny, __shfl_xor(miny, off));
    maxy = max(maxy, __shfl_xor(maxy, off));
    minx = min(minx, __shfl_xor(minx, off));
    maxx = max(maxx, __shfl_xor(maxx, off));
  }
  if (lane == 0) { r0[wv] = miny; r1[wv] = maxy; r2[wv] = minx; r3[wv] = maxx; }
  __syncthreads();
  if (t == 0) {
    int mny = r0[0], mxy = r1[0], mnx = r2[0], mxx = r3[0];
    for (int wI = 1; wI < 4; ++wI) {
      mny = min(mny, r0[wI]); mxy = max(mxy, r1[wI]);
      mnx = min(mnx, r2[wI]); mxx = max(mxx, r3[wI]);
    }
    const bool any = (mxy >= 0);
    const int mh2 = (mxy - mny) / 2;
    const int mw2 = (mxx - mnx) / 2;
    const bool valid = any && (mh2 > 4) && (mw2 > 4);

    u32 kb0 = 0, kb1 = (u32)b; tf2x32(ks0, ks1, kb0, kb1);   // keys[b]
    u32 kh0 = 0, kh1 = 1; tf2x32(kb0, kb1, kh0, kh1);        // k_h
    u32 kw0 = 0, kw1 = 2; tf2x32(kb0, kb1, kw0, kw1);        // k_w
    const float uh = u01(rbits_scalar(kh0, kh1));
    const float uw = u01(rbits_scalar(kw0, kw1));

    const int cy = sc_ix / HW, cx = sc_ix % HW;
    const int h = 4 + (int)(uh * (float)max(mh2 - 4, 1));
    const int w = 4 + (int)(uw * (float)max(mw2 - 4, 1));
    SP p;
    p.thr = thr;
    p.hs = max(cy - h, 0); p.he = min(cy + h, HW);
    p.wss = max(cx - w, 0); p.wee = min(cx + w, HW);
    p.doit = valid ? 1 : 0;
    p.pad0 = 0; p.pad1 = 0;
    sp[b] = p;
  }
}

// ---------------------------------------------------------------------------
// Kernel 3 (round-6 verbatim — the proven 6.2 TB/s heavy kernel): one block =
// 256 consecutive float4 of one sample; inline threefry only for erased
// lanes; nontemporal streaming stores; single touch per output line.
// ---------------------------------------------------------------------------
__global__ __launch_bounds__(256) void k_apply(const float* __restrict__ x,
                                               const SP* __restrict__ sp,
                                               float* __restrict__ out,
                                               u32 kn0, u32 kn1) {
  const int bid = blockIdx.x;
  const int b   = bid / APB;
  const int i   = (bid % APB) * 256 + threadIdx.x;   // float4 index in sample
  const SP p = sp[b];
  const vf4 vv = ((const vf4*)(x + (size_t)b * S))[i];
  vf4* __restrict__ os = (vf4*)(out + (size_t)b * S);
  vf4* __restrict__ ms = (vf4*)(out + (size_t)NTOT + (size_t)b * S);

  const int base = i * 4;
  const int y = base / HW, x0 = base % HW;
  const bool yin = p.doit && (y > p.hs) && (y < p.he) && (y > 0);
  const u32 eoff = (u32)b * (u32)S;

  vf4 o, m;
  int need = 0;
#pragma unroll
  for (int j = 0; j < 4; ++j) {
    const float val = vv[j];
    // inp = 0.6*x + 0.2 -- no fma contraction
    const float inp = __fadd_rn(__fmul_rn(0.6f, val), 0.2f);
    const int xx = x0 + j;
    const bool mz = yin && (val > p.thr) && (xx > p.wss) && (xx < p.wee) && (xx > 0);
    m[j] = mz ? 0.0f : 1.0f;
    o[j] = inp;
    if (mz) need |= 1 << j;
  }
  if (need) {
#pragma unroll
    for (int j = 0; j < 4; ++j) {
      if (need & (1 << j)) {
        const float kp = fminf(fmaxf(__fsub_rn(1.0f, o[j]), 0.0f), 1.0f);
        u32 c0 = 0u, c1 = eoff + (u32)(base + j);
        tf2x32(kn0, kn1, c0, c1);
        if (!(u01(c0 ^ c1) < kp)) o[j] = 0.0f;   // inp * 0
      }
    }
  }
  __builtin_nontemporal_store(o, &os[i]);
  __builtin_nontemporal_store(m, &ms[i]);
}

// ---------------------------------------------------------------------------
extern "C" void kernel_launch(void* const* d_in, const int* in_sizes, int n_in,
                              void* d_out, int out_size, void* d_ws, size_t ws_size,
                              hipStream_t stream) {
  const float* x = (const float*)d_in[0];
  float* out = (float*)d_out;
  SP*    sp    = (SP*)d_ws;
  float* fdata = (float*)((char*)d_ws + 16384);

  // host-side key derivation: root = key(42) = (0,42)
  u32 kf0 = 0, kf1 = 0; tf2x32(0u, 42u, kf0, kf1);   // k_factor = split[0]
  u32 ks0 = 0, ks1 = 1; tf2x32(0u, 42u, ks0, ks1);   // k_samples = split[1]
  u32 kn0 = 0, kn1 = 2; tf2x32(0u, 42u, kn0, kn1);   // k_noise  = split[2]
  float factor = fmaxf(0.0f, u01(rbits_scalar(kf0, kf1)) * 0.5f);

  // host-side per-sample apply flags (pure RNG, deterministic)
  AMask am;
  for (int i = 0; i < 8; ++i) am.m[i] = 0ull;
  for (int b = 0; b < BATCH; ++b) {
    u32 kb0 = 0, kb1 = (u32)b; tf2x32(ks0, ks1, kb0, kb1);
    u32 ka0 = 0, ka1 = 0; tf2x32(kb0, kb1, ka0, ka1);
    if (u01(rbits_scalar(ka0, ka1)) < 0.5f) am.m[b >> 6] |= 1ull << (b & 63);
  }

  hipLaunchKernelGGL(k_stats, dim3(BATCH * 4), dim3(256), 0, stream,
                     x, fdata, am);
  hipLaunchKernelGGL(k_box,   dim3(BATCH), dim3(256), 0, stream,
                     fdata, sp, factor, ks0, ks1, am);
  hipLaunchKernelGGL(k_apply, dim3(BATCH * APB), dim3(256), 0, stream,
                     x, sp, out, kn0, kn1);
}

// Round 13
// 63.001 us; speedup vs baseline: 1.6436x; 1.1076x over previous
//
#include <hip/hip_runtime.h>
#include <cstdint>

typedef unsigned int u32;
typedef float vf4 __attribute__((ext_vector_type(4)));

// ---------------------------------------------------------------------------
// Threefry-2x32 (20 rounds) — validated bit-exact vs JAX in round 1
// (jax_threefry_partitionable=True semantics).
//   split(key, n)[i]           = threefry2x32(key, (0, i))
//   random_bits(key,32,shape)e = r0 ^ r1 of threefry2x32(key, (0, e))
// ---------------------------------------------------------------------------
#define TF_R4(a,b,r1,r2,r3,r4) \
  a += b; b = (b<<r1)|(b>>(32-r1)); b ^= a; \
  a += b; b = (b<<r2)|(b>>(32-r2)); b ^= a; \
  a += b; b = (b<<r3)|(b>>(32-r3)); b ^= a; \
  a += b; b = (b<<r4)|(b>>(32-r4)); b ^= a;

__host__ __device__ inline void tf2x32(u32 k0, u32 k1, u32& x0, u32& x1) {
  const u32 k2 = k0 ^ k1 ^ 0x1BD11BDAu;
  u32 a = x0 + k0, b = x1 + k1;
  TF_R4(a,b,13,15,26,6)   a += k1; b += k2 + 1u;
  TF_R4(a,b,17,29,16,24)  a += k2; b += k0 + 2u;
  TF_R4(a,b,13,15,26,6)   a += k0; b += k1 + 3u;
  TF_R4(a,b,17,29,16,24)  a += k1; b += k2 + 4u;
  TF_R4(a,b,13,15,26,6)   a += k2; b += k0 + 5u;
  x0 = a; x1 = b;
}

__host__ __device__ inline float u01(u32 bits) {
  union { u32 u; float f; } c; c.u = (bits >> 9) | 0x3f800000u;
  return c.f - 1.0f;
}
__host__ __device__ inline u32 rbits_scalar(u32 k0, u32 k1) {
  u32 a = 0, b = 0; tf2x32(k0, k1, a, b); return a ^ b;
}

// problem constants
#define BATCH   512
#define HW      224
#define S       50176     /* 224*224 */
#define NTOT    25690112
#define APB     49        /* apply blocks per sample: S4/256 */
#define FSTR    1152      /* ws floats per sample */
#define NSTATB  2048      /* stats blocks in pass 1 */

struct SP { float thr; int hs, he, wss, wee, doit; int pad0, pad1; };
struct AMask { unsigned long long m[8]; };   // host-computed apply flags
// ws layout: [0, 16384) SP[512]; [16384, ...) fdata[512][FSTR] floats
//   fdata per sample: [0,224) rowmax; [224,1120) colmax quarter partials;
//                     [1120,1132) per-quarter {max, argmax-bits, min} x 4

__device__ __forceinline__ bool applyb(const AMask& am, int b) {
  return (am.m[b >> 6] >> (b & 63)) & 1ull;
}

// ---------------------------------------------------------------------------
// Pass 1 — heterogeneous grid, zero cross-block communication:
//   blocks [0, NSTATB): round-12 proven stats body (apply samples only)
//   blocks [NSTATB, +25088): stream out=0.6x+0.2, mask=1 for NON-apply
//     samples (their output depends on nothing — hides the stats read)
// ---------------------------------------------------------------------------
__global__ __launch_bounds__(256) void k_pass1(const float* __restrict__ x,
                                               float* __restrict__ out,
                                               float* __restrict__ fdata,
                                               AMask am) {
  const int bid = blockIdx.x;
  const int t = threadIdx.x;

  if (bid >= NSTATB) {
    // ---------------- non-apply streaming writer ----------------
    const int idx = bid - NSTATB;
    const int b = idx / APB;
    if (applyb(am, b)) return;               // apply samples: written in D3
    const int i = (idx % APB) * 256 + t;     // float4 index in sample
    const vf4 v = ((const vf4*)(x + (size_t)b * S))[i];
    vf4 o;
    // inp = 0.6*x + 0.2 -- no fma contraction (match XLA)
    o[0] = __fadd_rn(__fmul_rn(0.6f, v[0]), 0.2f);
    o[1] = __fadd_rn(__fmul_rn(0.6f, v[1]), 0.2f);
    o[2] = __fadd_rn(__fmul_rn(0.6f, v[2]), 0.2f);
    o[3] = __fadd_rn(__fmul_rn(0.6f, v[3]), 0.2f);
    const vf4 ones = (vf4){1.f, 1.f, 1.f, 1.f};
    __builtin_nontemporal_store(o,    &((vf4*)(out + (size_t)b * S))[i]);
    __builtin_nontemporal_store(ones, &((vf4*)(out + (size_t)NTOT + (size_t)b * S))[i]);
    return;
  }

  // ---------------- stats quarter (round-12 proven body) ----------------
  const int b = bid >> 2, q = bid & 3;
  if (!applyb(am, b)) return;                // non-apply: stats unused

  const int lane = t & 63, wv = t >> 6;
  const float* __restrict__ xs = x + (size_t)b * S;
  float* __restrict__ base = fdata + (size_t)b * FSTR;
  const bool act = lane < 56;

  vf4 cmax = (vf4){0.f, 0.f, 0.f, 0.f};      // x in [0,1) -> 0 neutral
  float amax = -1.f; int aidx = 0x7fffffff; float amin = 2.f;

#pragma unroll
  for (int k = 0; k < 14; ++k) {
    const int r = q * 56 + wv * 14 + k;
    vf4 v = (vf4){-1.f, -1.f, -1.f, -1.f};
    if (act) v = ((const vf4*)(xs + (size_t)r * HW))[lane];
    float rv = fmaxf(fmaxf(v[0], v[1]), fmaxf(v[2], v[3]));
    if (act) {
      cmax[0] = fmaxf(cmax[0], v[0]); cmax[1] = fmaxf(cmax[1], v[1]);
      cmax[2] = fmaxf(cmax[2], v[2]); cmax[3] = fmaxf(cmax[3], v[3]);
      const int fb = r * HW + lane * 4;
      if (v[0] > amax) { amax = v[0]; aidx = fb; }
      if (v[1] > amax) { amax = v[1]; aidx = fb + 1; }
      if (v[2] > amax) { amax = v[2]; aidx = fb + 2; }
      if (v[3] > amax) { amax = v[3]; aidx = fb + 3; }
      amin = fminf(amin, fminf(fminf(v[0], v[1]), fminf(v[2], v[3])));
    }
    for (int off = 32; off; off >>= 1) rv = fmaxf(rv, __shfl_xor(rv, off));
    if (lane == 0) base[r] = rv;             // rowmax
  }
  for (int off = 32; off; off >>= 1) {
    float v2 = __shfl_xor(amax, off);
    int   i2 = __shfl_xor(aidx, off);
    float n2 = __shfl_xor(amin, off);
    if (v2 > amax || (v2 == amax && i2 < aidx)) { amax = v2; aidx = i2; }
    amin = fminf(amin, n2);
  }
  __shared__ vf4 cmw[4][56];
  __shared__ float wmx[4]; __shared__ int wix[4]; __shared__ float wmn[4];
  if (act) cmw[wv][lane] = cmax;
  if (lane == 0) { wmx[wv] = amax; wix[wv] = aidx; wmn[wv] = amin; }
  __syncthreads();
  if (t < 56) {
    vf4 a = cmw[0][t], c1 = cmw[1][t], c2 = cmw[2][t], c3 = cmw[3][t];
    vf4 m;
    m[0] = fmaxf(fmaxf(a[0], c1[0]), fmaxf(c2[0], c3[0]));
    m[1] = fmaxf(fmaxf(a[1], c1[1]), fmaxf(c2[1], c3[1]));
    m[2] = fmaxf(fmaxf(a[2], c1[2]), fmaxf(c2[2], c3[2]));
    m[3] = fmaxf(fmaxf(a[3], c1[3]), fmaxf(c2[3], c3[3]));
    ((vf4*)(base + 224 + q * 224))[t] = m;   // colmax quarter partial
  }
  if (t == 0) {
    float mx = wmx[0]; int ix = wix[0]; float mn = wmn[0];
    for (int wI = 1; wI < 4; ++wI) {
      if (wmx[wI] > mx || (wmx[wI] == mx && wix[wI] < ix)) { mx = wmx[wI]; ix = wix[wI]; }
      mn = fminf(mn, wmn[wI]);
    }
    base[1120 + q * 3 + 0] = mx;
    base[1120 + q * 3 + 1] = __int_as_float(ix);
    base[1120 + q * 3 + 2] = mn;
  }
}

// ---------------------------------------------------------------------------
// Kernel 2 (round-12 verbatim): one block per sample; derives thr / erase box
// from ws partials; writes SP. Non-apply: doit=0 immediately.
// ---------------------------------------------------------------------------
__global__ __launch_bounds__(256) void k_box(const float* __restrict__ fdata,
                                             SP* __restrict__ sp,
                                             float factor, u32 ks0, u32 ks1,
                                             AMask am) {
  const int b = blockIdx.x;
  const int t = threadIdx.x;
  const int lane = t & 63, wv = t >> 6;

  if (!applyb(am, b)) {
    if (t == 0) {
      SP p; p.thr = 0.f; p.hs = 0; p.he = 0; p.wss = 0; p.wee = 0;
      p.doit = 0; p.pad0 = 0; p.pad1 = 0;
      sp[b] = p;
    }
    return;
  }

  const float* __restrict__ base = fdata + (size_t)b * FSTR;
  __shared__ float sc_thr; __shared__ int sc_ix;
  __shared__ int r0[4], r1[4], r2[4], r3[4];

  if (t == 0) {
    float mx = -1.f; int ix = 0x7fffffff; float mn = 2.f;
#pragma unroll
    for (int q2 = 0; q2 < 4; ++q2) {
      const float v = base[1120 + q2 * 3 + 0];
      const int   i = __float_as_int(base[1120 + q2 * 3 + 1]);
      const float n = base[1120 + q2 * 3 + 2];
      if (v > mx || (v == mx && i < ix)) { mx = v; ix = i; }
      mn = fminf(mn, n);
    }
    // thr = mx - (mx - mn) * factor -- no fma contraction (match XLA)
    sc_thr = __fsub_rn(mx, __fmul_rn(__fsub_rn(mx, mn), factor));
    sc_ix = ix;
  }
  __syncthreads();
  const float thr = sc_thr;

  int miny = HW, maxy = -1, minx = HW, maxx = -1;
  if (t < HW) {
    if (base[t] > thr) { miny = t; maxy = t; }
    const float c0 = base[224 + t],       c1 = base[224 + 224 + t];
    const float c2 = base[224 + 448 + t], c3 = base[224 + 672 + t];
    if (fmaxf(fmaxf(c0, c1), fmaxf(c2, c3)) > thr) { minx = t; maxx = t; }
  }
  for (int off = 32; off; off >>= 1) {
    miny = min(miny, __shfl_xor(miny, off));
    maxy = max(maxy, __shfl_xor(maxy, off));
    minx = min(minx, __shfl_xor(minx, off));
    maxx = max(maxx, __shfl_xor(maxx, off));
  }
  if (lane == 0) { r0[wv] = miny; r1[wv] = maxy; r2[wv] = minx; r3[wv] = maxx; }
  __syncthreads();
  if (t == 0) {
    int mny = r0[0], mxy = r1[0], mnx = r2[0], mxx = r3[0];
    for (int wI = 1; wI < 4; ++wI) {
      mny = min(mny, r0[wI]); mxy = max(mxy, r1[wI]);
      mnx = min(mnx, r2[wI]); mxx = max(mxx, r3[wI]);
    }
    const bool any = (mxy >= 0);
    const int mh2 = (mxy - mny) / 2;
    const int mw2 = (mxx - mnx) / 2;
    const bool valid = any && (mh2 > 4) && (mw2 > 4);

    u32 kb0 = 0, kb1 = (u32)b; tf2x32(ks0, ks1, kb0, kb1);   // keys[b]
    u32 kh0 = 0, kh1 = 1; tf2x32(kb0, kb1, kh0, kh1);        // k_h
    u32 kw0 = 0, kw1 = 2; tf2x32(kb0, kb1, kw0, kw1);        // k_w
    const float uh = u01(rbits_scalar(kh0, kh1));
    const float uw = u01(rbits_scalar(kw0, kw1));

    const int cy = sc_ix / HW, cx = sc_ix % HW;
    const int h = 4 + (int)(uh * (float)max(mh2 - 4, 1));
    const int w = 4 + (int)(uw * (float)max(mw2 - 4, 1));
    SP p;
    p.thr = thr;
    p.hs = max(cy - h, 0); p.he = min(cy + h, HW);
    p.wss = max(cx - w, 0); p.wee = min(cx + w, HW);
    p.doit = valid ? 1 : 0;
    p.pad0 = 0; p.pad1 = 0;
    sp[b] = p;
  }
}

// ---------------------------------------------------------------------------
// Kernel 3 (round-12 k_apply + non-apply early exit): apply samples only —
// non-apply output was already written in pass 1. SGPR bitmask check, no
// memory touched on the exit path.
// ---------------------------------------------------------------------------
__global__ __launch_bounds__(256) void k_apply(const float* __restrict__ x,
                                               const SP* __restrict__ sp,
                                               float* __restrict__ out,
                                               u32 kn0, u32 kn1, AMask am) {
  const int bid = blockIdx.x;
  const int b   = bid / APB;
  if (!applyb(am, b)) return;                // written in pass 1

  const int i   = (bid % APB) * 256 + threadIdx.x;   // float4 index in sample
  const SP p = sp[b];
  const vf4 vv = ((const vf4*)(x + (size_t)b * S))[i];
  vf4* __restrict__ os = (vf4*)(out + (size_t)b * S);
  vf4* __restrict__ ms = (vf4*)(out + (size_t)NTOT + (size_t)b * S);

  const int base = i * 4;
  const int y = base / HW, x0 = base % HW;
  const bool yin = p.doit && (y > p.hs) && (y < p.he) && (y > 0);
  const u32 eoff = (u32)b * (u32)S;

  vf4 o, m;
  int need = 0;
#pragma unroll
  for (int j = 0; j < 4; ++j) {
    const float val = vv[j];
    // inp = 0.6*x + 0.2 -- no fma contraction
    const float inp = __fadd_rn(__fmul_rn(0.6f, val), 0.2f);
    const int xx = x0 + j;
    const bool mz = yin && (val > p.thr) && (xx > p.wss) && (xx < p.wee) && (xx > 0);
    m[j] = mz ? 0.0f : 1.0f;
    o[j] = inp;
    if (mz) need |= 1 << j;
  }
  if (need) {
#pragma unroll
    for (int j = 0; j < 4; ++j) {
      if (need & (1 << j)) {
        const float kp = fminf(fmaxf(__fsub_rn(1.0f, o[j]), 0.0f), 1.0f);
        u32 c0 = 0u, c1 = eoff + (u32)(base + j);
        tf2x32(kn0, kn1, c0, c1);
        if (!(u01(c0 ^ c1) < kp)) o[j] = 0.0f;   // inp * 0
      }
    }
  }
  __builtin_nontemporal_store(o, &os[i]);
  __builtin_nontemporal_store(m, &ms[i]);
}

// ---------------------------------------------------------------------------
extern "C" void kernel_launch(void* const* d_in, const int* in_sizes, int n_in,
                              void* d_out, int out_size, void* d_ws, size_t ws_size,
                              hipStream_t stream) {
  const float* x = (const float*)d_in[0];
  float* out = (float*)d_out;
  SP*    sp    = (SP*)d_ws;
  float* fdata = (float*)((char*)d_ws + 16384);

  // host-side key derivation: root = key(42) = (0,42)
  u32 kf0 = 0, kf1 = 0; tf2x32(0u, 42u, kf0, kf1);   // k_factor = split[0]
  u32 ks0 = 0, ks1 = 1; tf2x32(0u, 42u, ks0, ks1);   // k_samples = split[1]
  u32 kn0 = 0, kn1 = 2; tf2x32(0u, 42u, kn0, kn1);   // k_noise  = split[2]
  float factor = fmaxf(0.0f, u01(rbits_scalar(kf0, kf1)) * 0.5f);

  // host-side per-sample apply flags (pure RNG, deterministic)
  AMask am;
  for (int i = 0; i < 8; ++i) am.m[i] = 0ull;
  for (int b = 0; b < BATCH; ++b) {
    u32 kb0 = 0, kb1 = (u32)b; tf2x32(ks0, ks1, kb0, kb1);
    u32 ka0 = 0, ka1 = 0; tf2x32(kb0, kb1, ka0, ka1);
    if (u01(rbits_scalar(ka0, ka1)) < 0.5f) am.m[b >> 6] |= 1ull << (b & 63);
  }

  hipLaunchKernelGGL(k_pass1, dim3(NSTATB + BATCH * APB), dim3(256), 0, stream,
                     x, out, fdata, am);
  hipLaunchKernelGGL(k_box,   dim3(BATCH), dim3(256), 0, stream,
                     fdata, sp, factor, ks0, ks1, am);
  hipLaunchKernelGGL(k_apply, dim3(BATCH * APB), dim3(256), 0, stream,
                     x, sp, out, kn0, kn1, am);
}